// Round 3
// baseline (317.372 us; speedup 1.0000x reference)
//
#include <hip/hip_runtime.h>

// MultiHeadAttn fused pipeline for MI355X (gfx950).
// B=2, S=2048, D=1024, H=16, HD=64. All GEMM-shaped compute in bf16 MFMA
// (16x16x32), softmax/LN in f32. Round 3: mask input is int32 (harness passes
// bool as int) -> convert to uint8 once, then attention reads bytes.

#define NB 2
#define SS 2048
#define DDIM 1024
#define NH 16
#define HDIM 64
#define MROWS (NB * SS)  // 4096

typedef unsigned short u16;
typedef short bf16x8 __attribute__((ext_vector_type(8)));
typedef float f32x4 __attribute__((ext_vector_type(4)));

typedef const __attribute__((address_space(1))) void GASV;
typedef __attribute__((address_space(3))) void LASV;

__device__ __forceinline__ u16 f2bf(float f) {
  unsigned u = __builtin_bit_cast(unsigned, f);
  u += 0x7FFFu + ((u >> 16) & 1u);  // RNE; inputs finite
  return (u16)(u >> 16);
}

// ---------------- f32 -> bf16 elementwise ----------------
__global__ __launch_bounds__(256) void cvt_bf16_k(const float* __restrict__ in,
                                                  u16* __restrict__ out) {
  size_t i = ((size_t)blockIdx.x * 256 + threadIdx.x) * 4;
  float4 v = *(const float4*)(in + i);
  uint2 o;
  u16* po = (u16*)&o;
  po[0] = f2bf(v.x); po[1] = f2bf(v.y); po[2] = f2bf(v.z); po[3] = f2bf(v.w);
  *(uint2*)(out + i) = o;
}

// ---------------- mask int32 -> uint8 ----------------
__global__ __launch_bounds__(256) void cvt_mask_k(const int* __restrict__ in,
                                                  unsigned char* __restrict__ out) {
  size_t i = ((size_t)blockIdx.x * 256 + threadIdx.x) * 16;
  int4 a = *(const int4*)(in + i);
  int4 b = *(const int4*)(in + i + 4);
  int4 c = *(const int4*)(in + i + 8);
  int4 d = *(const int4*)(in + i + 12);
  int4 o;
  unsigned char* po = (unsigned char*)&o;
  po[0] = a.x != 0; po[1] = a.y != 0; po[2] = a.z != 0; po[3] = a.w != 0;
  po[4] = b.x != 0; po[5] = b.y != 0; po[6] = b.z != 0; po[7] = b.w != 0;
  po[8] = c.x != 0; po[9] = c.y != 0; po[10] = c.z != 0; po[11] = c.w != 0;
  po[12] = d.x != 0; po[13] = d.y != 0; po[14] = d.z != 0; po[15] = d.w != 0;
  *(int4*)(out + i) = o;
}

// ---------------- W[K][N] f32 -> WT[N][K] bf16 ----------------
__global__ __launch_bounds__(256) void transpose_cvt_w(const float* __restrict__ W,
                                                       u16* __restrict__ WT) {
  __shared__ u16 t[64][65];
  const int k0 = blockIdx.x * 64, n0 = blockIdx.y * 64;
  const int tid = threadIdx.x;
  const int r = tid >> 4;          // 0..15
  const int c4 = (tid & 15) * 4;   // col group
#pragma unroll
  for (int it = 0; it < 4; ++it) {
    int k = r + it * 16;
    float4 v = *(const float4*)&W[(size_t)(k0 + k) * DDIM + n0 + c4];
    t[c4 + 0][k] = f2bf(v.x);
    t[c4 + 1][k] = f2bf(v.y);
    t[c4 + 2][k] = f2bf(v.z);
    t[c4 + 3][k] = f2bf(v.w);
  }
  __syncthreads();
#pragma unroll
  for (int it = 0; it < 4; ++it) {
    int n = r + it * 16;
    uint2 o;
    u16* po = (u16*)&o;
#pragma unroll
    for (int j = 0; j < 4; ++j) po[j] = t[n][c4 + j];
    *(uint2*)&WT[(size_t)(n0 + n) * DDIM + k0 + c4] = o;
  }
}

// ---------------- Vp (B,S,D) bf16 -> VpT (B*H, HD, S) bf16 ----------------
__global__ __launch_bounds__(256) void transpose_v(const u16* __restrict__ Vp,
                                                   u16* __restrict__ VpT) {
  __shared__ u16 t[64][65];
  const int bh = blockIdx.y, b = bh >> 4, h = bh & 15;
  const int s0 = blockIdx.x * 64;
  const int tid = threadIdx.x;
  const int r = tid >> 3;        // 0..31
  const int c8 = (tid & 7) * 8;  // 8-elem chunk
  const u16* src = Vp + ((size_t)(b * SS + s0)) * DDIM + h * 64;
#pragma unroll
  for (int it = 0; it < 2; ++it) {
    int s = r + it * 32;
    int4 v = *(const int4*)(src + (size_t)s * DDIM + c8);
    u16* pv = (u16*)&v;
#pragma unroll
    for (int j = 0; j < 8; ++j) t[c8 + j][s] = pv[j];
  }
  __syncthreads();
  u16* dst = VpT + (size_t)bh * 64 * SS + s0;
#pragma unroll
  for (int it = 0; it < 2; ++it) {
    int d = r + it * 32;
    int4 o;
    u16* po = (u16*)&o;
#pragma unroll
    for (int j = 0; j < 8; ++j) po[j] = t[d][c8 + j];
    *(int4*)(dst + (size_t)d * SS + c8) = o;
  }
}

// ---------------- GEMM: C[M][N] = A[M][K] * BT[N][K]^T + bias ----------------
// 128x128 tile, BK=64, 4 waves (2x2), 16x16x32 bf16 MFMA. m97-lite structure.
template <int OUTF32>
__global__ __launch_bounds__(256) void gemm_bt(const u16* __restrict__ A,
                                               const u16* __restrict__ BT,
                                               const float* __restrict__ bias,
                                               void* __restrict__ C, int Ndim,
                                               int Kdim) {
  __shared__ __align__(16) u16 Al[128][64];
  __shared__ __align__(16) u16 Bl[128][64];
  const int tid = threadIdx.x;
  const int wid = tid >> 6, lane = tid & 63;
  const int wm = (wid >> 1) * 64, wn = (wid & 1) * 64;
  const int rowA0 = blockIdx.x * 128, colB0 = blockIdx.y * 128;
  f32x4 acc[4][4] = {};

  const int rl = lane >> 3;        // 0..7 row within 8-row slab
  const int ce = (lane & 7) * 8;   // elem offset within row
  for (int kt = 0; kt < Kdim; kt += 64) {
#pragma unroll
    for (int c = 0; c < 4; ++c) {
      int rt = wid * 32 + c * 8;
      const u16* ga = A + (size_t)(rowA0 + rt + rl) * Kdim + kt + ce;
      const u16* gb = BT + (size_t)(colB0 + rt + rl) * Kdim + kt + ce;
      __builtin_amdgcn_global_load_lds((GASV*)ga, (LASV*)((char*)&Al[0][0] + rt * 128), 16, 0, 0);
      __builtin_amdgcn_global_load_lds((GASV*)gb, (LASV*)((char*)&Bl[0][0] + rt * 128), 16, 0, 0);
    }
    __syncthreads();
#pragma unroll
    for (int kk = 0; kk < 64; kk += 32) {
      bf16x8 af[4], bfr[4];
#pragma unroll
      for (int i = 0; i < 4; ++i)
        af[i] = *(const bf16x8*)&Al[wm + i * 16 + (lane & 15)][kk + (lane >> 4) * 8];
#pragma unroll
      for (int j = 0; j < 4; ++j)
        bfr[j] = *(const bf16x8*)&Bl[wn + j * 16 + (lane & 15)][kk + (lane >> 4) * 8];
#pragma unroll
      for (int i = 0; i < 4; ++i)
#pragma unroll
        for (int j = 0; j < 4; ++j)
          acc[i][j] = __builtin_amdgcn_mfma_f32_16x16x32_bf16(af[i], bfr[j], acc[i][j], 0, 0, 0);
    }
    __syncthreads();
  }
#pragma unroll
  for (int i = 0; i < 4; ++i) {
#pragma unroll
    for (int j = 0; j < 4; ++j) {
      int col = colB0 + wn + j * 16 + (lane & 15);
      float bv = bias[col];
#pragma unroll
      for (int r = 0; r < 4; ++r) {
        int row = rowA0 + wm + i * 16 + (lane >> 4) * 4 + r;
        float v = acc[i][j][r] + bv;
        if (OUTF32)
          ((float*)C)[(size_t)row * Ndim + col] = v;
        else
          ((u16*)C)[(size_t)row * Ndim + col] = f2bf(v);
      }
    }
  }
}

// ---------------- Flash attention ----------------
// grid: (S/64 q-tiles, B*H). 4 waves; wave w owns q-rows [w*16, w*16+16).
__global__ __launch_bounds__(256) void attn_fwd(const u16* __restrict__ Qp,
                                                const u16* __restrict__ Kp,
                                                const u16* __restrict__ VpT,
                                                const unsigned char* __restrict__ mask,
                                                u16* __restrict__ O) {
  __shared__ __align__(16) u16 Kl[64][64];            // [kv][d]
  __shared__ __align__(16) u16 Vl[64][64];            // [d][kv]
  __shared__ __align__(16) unsigned char Ml[64][64];  // [q][kv]
  __shared__ __align__(16) u16 Pl[4][16][64];         // per-wave P
  const int tid = threadIdx.x, wid = tid >> 6, lane = tid & 63;
  const int bh = blockIdx.y, b = bh >> 4, h = bh & 15;
  const int q0 = blockIdx.x * 64;

  bf16x8 qf[2];
  {
    const u16* qb = Qp + (size_t)(b * SS + q0 + wid * 16 + (lane & 15)) * DDIM +
                    h * 64 + (lane >> 4) * 8;
    qf[0] = *(const bf16x8*)qb;
    qf[1] = *(const bf16x8*)(qb + 32);
  }
  float m_run[4], l_run[4];
  f32x4 accO[4];
#pragma unroll
  for (int j = 0; j < 4; ++j) { m_run[j] = -__builtin_inff(); l_run[j] = 0.f; }
#pragma unroll
  for (int f = 0; f < 4; ++f) accO[f] = (f32x4){0.f, 0.f, 0.f, 0.f};

  const u16* Kgb = Kp + (size_t)b * SS * DDIM + h * 64;
  const u16* Vgb = VpT + (size_t)bh * 64 * SS;
  const unsigned char* Mgb = mask + (size_t)b * SS * SS + (size_t)q0 * SS;
  const int rl = lane >> 3, ce = (lane & 7) * 8;
  const int mr = tid >> 2, mc = (tid & 3) * 16;

  for (int kv0 = 0; kv0 < SS; kv0 += 64) {
#pragma unroll
    for (int c = 0; c < 2; ++c) {
      int rt = wid * 16 + c * 8;
      __builtin_amdgcn_global_load_lds((GASV*)(Kgb + (size_t)(kv0 + rt + rl) * DDIM + ce),
                                       (LASV*)((char*)&Kl[0][0] + rt * 128), 16, 0, 0);
      __builtin_amdgcn_global_load_lds((GASV*)(Vgb + (size_t)(rt + rl) * SS + kv0 + ce),
                                       (LASV*)((char*)&Vl[0][0] + rt * 128), 16, 0, 0);
    }
    *(int4*)&Ml[mr][mc] = *(const int4*)(Mgb + (size_t)mr * SS + kv0 + mc);
    __syncthreads();

    // scores: D[q][kv] = sum_d Q[q][d] K[kv][d], * 1/8, mask -> -inf
    f32x4 sc[4];
#pragma unroll
    for (int fn = 0; fn < 4; ++fn) {
      f32x4 c = (f32x4){0.f, 0.f, 0.f, 0.f};
#pragma unroll
      for (int ks = 0; ks < 2; ++ks) {
        bf16x8 kf = *(const bf16x8*)&Kl[fn * 16 + (lane & 15)][ks * 32 + (lane >> 4) * 8];
        c = __builtin_amdgcn_mfma_f32_16x16x32_bf16(qf[ks], kf, c, 0, 0, 0);
      }
      sc[fn] = c;
    }
    const int rbase = (lane >> 4) * 4, cbase = lane & 15;
#pragma unroll
    for (int fn = 0; fn < 4; ++fn)
#pragma unroll
      for (int j = 0; j < 4; ++j) {
        float s = sc[fn][j] * 0.125f;
        // mask row is BLOCK-local q row: wave offset wid*16 required
        if (Ml[wid * 16 + rbase + j][fn * 16 + cbase]) s = -__builtin_inff();
        sc[fn][j] = s;
      }
    // online softmax (per q-row; 16-lane group reduce)
    float bmax[4];
#pragma unroll
    for (int j = 0; j < 4; ++j)
      bmax[j] = fmaxf(fmaxf(sc[0][j], sc[1][j]), fmaxf(sc[2][j], sc[3][j]));
#pragma unroll
    for (int off = 1; off < 16; off <<= 1)
#pragma unroll
      for (int j = 0; j < 4; ++j) bmax[j] = fmaxf(bmax[j], __shfl_xor(bmax[j], off, 64));
    float alpha[4];
#pragma unroll
    for (int j = 0; j < 4; ++j) {
      float mn = fmaxf(m_run[j], bmax[j]);
      alpha[j] = (m_run[j] == mn) ? 1.0f : __expf(m_run[j] - mn);  // -inf==-inf -> 1
      m_run[j] = mn;
    }
    float rsum[4] = {0.f, 0.f, 0.f, 0.f};
#pragma unroll
    for (int fn = 0; fn < 4; ++fn)
#pragma unroll
      for (int j = 0; j < 4; ++j) {
        float s = sc[fn][j];
        float p = (s == -__builtin_inff()) ? 0.f : __expf(s - m_run[j]);
        sc[fn][j] = p;
        rsum[j] += p;
      }
#pragma unroll
    for (int off = 1; off < 16; off <<= 1)
#pragma unroll
      for (int j = 0; j < 4; ++j) rsum[j] += __shfl_xor(rsum[j], off, 64);
#pragma unroll
    for (int j = 0; j < 4; ++j) l_run[j] = l_run[j] * alpha[j] + rsum[j];
#pragma unroll
    for (int f = 0; f < 4; ++f)
#pragma unroll
      for (int j = 0; j < 4; ++j) accO[f][j] *= alpha[j];

    // P -> LDS (bf16), then PV: D[q][d] += P[q][kv] V[kv][d]
#pragma unroll
    for (int fn = 0; fn < 4; ++fn)
#pragma unroll
      for (int j = 0; j < 4; ++j)
        Pl[wid][rbase + j][fn * 16 + cbase] = f2bf(sc[fn][j]);
    bf16x8 pf0 = *(const bf16x8*)&Pl[wid][lane & 15][(lane >> 4) * 8];
    bf16x8 pf1 = *(const bf16x8*)&Pl[wid][lane & 15][32 + (lane >> 4) * 8];
#pragma unroll
    for (int nd = 0; nd < 4; ++nd) {
      bf16x8 v0 = *(const bf16x8*)&Vl[nd * 16 + (lane & 15)][(lane >> 4) * 8];
      bf16x8 v1 = *(const bf16x8*)&Vl[nd * 16 + (lane & 15)][32 + (lane >> 4) * 8];
      accO[nd] = __builtin_amdgcn_mfma_f32_16x16x32_bf16(pf0, v0, accO[nd], 0, 0, 0);
      accO[nd] = __builtin_amdgcn_mfma_f32_16x16x32_bf16(pf1, v1, accO[nd], 0, 0, 0);
    }
    __syncthreads();
  }
#pragma unroll
  for (int nd = 0; nd < 4; ++nd)
#pragma unroll
    for (int j = 0; j < 4; ++j) {
      int row = q0 + wid * 16 + (lane >> 4) * 4 + j;
      int col = h * 64 + nd * 16 + (lane & 15);
      O[(size_t)(b * SS + row) * DDIM + col] = f2bf(accO[nd][j] / l_run[j]);
    }
}

// ---------------- residual + LayerNorm (ddof=1, std+eps) ----------------
__global__ __launch_bounds__(256) void ln_res(const float* __restrict__ qin,
                                              const float* __restrict__ proj,
                                              const float* __restrict__ gamma,
                                              const float* __restrict__ beta,
                                              float* __restrict__ out) {
  const int row = blockIdx.x, tid = threadIdx.x;
  const size_t base = (size_t)row * DDIM + tid * 4;
  float4 a = *(const float4*)(qin + base);
  float4 p = *(const float4*)(proj + base);
  float x0 = a.x + p.x, x1 = a.y + p.y, x2 = a.z + p.z, x3 = a.w + p.w;
  float s = x0 + x1 + x2 + x3;
  __shared__ float red[4];
#pragma unroll
  for (int off = 32; off >= 1; off >>= 1) s += __shfl_xor(s, off, 64);
  const int wid = tid >> 6, lane = tid & 63;
  if (lane == 0) red[wid] = s;
  __syncthreads();
  float mean = (red[0] + red[1] + red[2] + red[3]) * (1.0f / DDIM);
  float d0 = x0 - mean, d1 = x1 - mean, d2 = x2 - mean, d3 = x3 - mean;
  float ss = d0 * d0 + d1 * d1 + d2 * d2 + d3 * d3;
#pragma unroll
  for (int off = 32; off >= 1; off >>= 1) ss += __shfl_xor(ss, off, 64);
  __syncthreads();
  if (lane == 0) red[wid] = ss;
  __syncthreads();
  float var = (red[0] + red[1] + red[2] + red[3]) * (1.0f / (DDIM - 1));
  float denom = sqrtf(var) + 1e-6f;
  float4 g = *(const float4*)(gamma + (size_t)tid * 4);
  float4 be = *(const float4*)(beta + (size_t)tid * 4);
  float4 o;
  o.x = g.x * d0 / denom + be.x;
  o.y = g.y * d1 / denom + be.y;
  o.z = g.z * d2 / denom + be.z;
  o.w = g.w * d3 / denom + be.w;
  *(float4*)(out + base) = o;
}

extern "C" void kernel_launch(void* const* d_in, const int* in_sizes, int n_in,
                              void* d_out, int out_size, void* d_ws, size_t ws_size,
                              hipStream_t stream) {
  const float* query = (const float*)d_in[0];
  const float* key = (const float*)d_in[1];
  const float* value = (const float*)d_in[2];
  const int* mask = (const int*)d_in[3];  // bool passed as int32
  const float* Wq = (const float*)d_in[4];
  const float* bq = (const float*)d_in[5];
  const float* Wk = (const float*)d_in[6];
  const float* bk = (const float*)d_in[7];
  const float* Wv = (const float*)d_in[8];
  const float* bv = (const float*)d_in[9];
  const float* Wo = (const float*)d_in[10];
  const float* bo = (const float*)d_in[11];
  const float* gamma = (const float*)d_in[12];
  const float* beta = (const float*)d_in[13];
  float* out = (float*)d_out;
  char* ws = (char*)d_ws;
  const size_t MB = 1ull << 20;
  // Workspace map (64 MB): buffers reused once producers/consumers are done.
  u16* qb = (u16*)(ws + 0 * MB);    // 8MB; later mask8, then proj
  u16* kb = (u16*)(ws + 8 * MB);    // 8MB; later overwritten by proj
  u16* vb = (u16*)(ws + 16 * MB);   // 8MB; later overwritten by VpT
  u16* WqT = (u16*)(ws + 24 * MB);  // 2MB each
  u16* WkT = (u16*)(ws + 26 * MB);
  u16* WvT = (u16*)(ws + 28 * MB);
  u16* WoT = (u16*)(ws + 30 * MB);
  u16* Qp = (u16*)(ws + 32 * MB);   // 8MB
  u16* Kp = (u16*)(ws + 40 * MB);   // 8MB
  u16* Vp = (u16*)(ws + 48 * MB);   // 8MB
  u16* VpT = (u16*)(ws + 16 * MB);  // over vb (dead after V-GEMM)
  u16* attn = (u16*)(ws + 56 * MB); // 8MB
  unsigned char* mask8 = (unsigned char*)(ws + 0 * MB);  // 8MB over qb (dead after Q-GEMM)
  float* proj = (float*)(ws + 0 * MB);  // 16MB over mask8+kb (dead after attn)

  const int NELEM = MROWS * DDIM;  // 4M
  cvt_bf16_k<<<NELEM / 1024, 256, 0, stream>>>(query, qb);
  cvt_bf16_k<<<NELEM / 1024, 256, 0, stream>>>(key, kb);
  cvt_bf16_k<<<NELEM / 1024, 256, 0, stream>>>(value, vb);
  transpose_cvt_w<<<dim3(16, 16), 256, 0, stream>>>(Wq, WqT);
  transpose_cvt_w<<<dim3(16, 16), 256, 0, stream>>>(Wk, WkT);
  transpose_cvt_w<<<dim3(16, 16), 256, 0, stream>>>(Wv, WvT);
  transpose_cvt_w<<<dim3(16, 16), 256, 0, stream>>>(Wo, WoT);
  gemm_bt<0><<<dim3(MROWS / 128, DDIM / 128), 256, 0, stream>>>(qb, WqT, bq, Qp, DDIM, DDIM);
  gemm_bt<0><<<dim3(MROWS / 128, DDIM / 128), 256, 0, stream>>>(kb, WkT, bk, Kp, DDIM, DDIM);
  gemm_bt<0><<<dim3(MROWS / 128, DDIM / 128), 256, 0, stream>>>(vb, WvT, bv, Vp, DDIM, DDIM);
  // mask cvt after Q-GEMM (qb region dead), before attn
  cvt_mask_k<<<(NB * SS * SS) / (256 * 16), 256, 0, stream>>>(mask, mask8);
  transpose_v<<<dim3(SS / 64, NB * NH), 256, 0, stream>>>(Vp, VpT);
  attn_fwd<<<dim3(SS / 64, NB * NH), 256, 0, stream>>>(Qp, Kp, VpT, mask8, attn);
  gemm_bt<1><<<dim3(MROWS / 128, DDIM / 128), 256, 0, stream>>>(attn, WoT, bo, proj, DDIM, DDIM);
  ln_res<<<MROWS, 256, 0, stream>>>(query, proj, gamma, beta, out);
}

// Round 4
// 286.748 us; speedup vs baseline: 1.1068x; 1.1068x over previous
//
#include <hip/hip_runtime.h>

// MultiHeadAttn fused pipeline for MI355X (gfx950).
// B=2, S=2048, D=1024, H=16, HD=64. Round 4:
//  - attn: K/V LDS XOR-swizzle (both-sides, pre-swizzled global source),
//    bitmask mask (ballot-packed, L2-resident), 2-phase double-buffered
//    prefetch, setprio around MFMA, Q pre-scaled by 1/8 in GEMM epilogue.
//  - GEMM: fused QKV projection (one launch), 2-phase double-buffer.

#define NB 2
#define SS 2048
#define DDIM 1024
#define NH 16
#define HDIM 64
#define MROWS (NB * SS)  // 4096

typedef unsigned short u16;
typedef unsigned long long u64;
typedef short bf16x8 __attribute__((ext_vector_type(8)));
typedef float f32x4 __attribute__((ext_vector_type(4)));

typedef const __attribute__((address_space(1))) void GASV;
typedef __attribute__((address_space(3))) void LASV;

__device__ __forceinline__ u16 f2bf(float f) {
  unsigned u = __builtin_bit_cast(unsigned, f);
  u += 0x7FFFu + ((u >> 16) & 1u);  // RNE; inputs finite
  return (u16)(u >> 16);
}

// ---------------- f32 -> bf16 elementwise ----------------
__global__ __launch_bounds__(256) void cvt_bf16_k(const float* __restrict__ in,
                                                  u16* __restrict__ out) {
  size_t i = ((size_t)blockIdx.x * 256 + threadIdx.x) * 4;
  float4 v = *(const float4*)(in + i);
  uint2 o;
  u16* po = (u16*)&o;
  po[0] = f2bf(v.x); po[1] = f2bf(v.y); po[2] = f2bf(v.z); po[3] = f2bf(v.w);
  *(uint2*)(out + i) = o;
}

// ---------------- mask int32 -> bitmask (64 kv per u64 word) ----------------
__global__ __launch_bounds__(256) void cvt_mask_bits(const int* __restrict__ in,
                                                     u64* __restrict__ out) {
  size_t w = ((size_t)blockIdx.x * 256 + threadIdx.x) >> 6;
  int lane = threadIdx.x & 63;
  int v = in[w * 64 + lane];
  u64 bits = __ballot(v != 0);  // bit l = (mask[w*64+l] != 0)
  if (lane == 0) out[w] = bits;
}

// ---------------- W[K][N] f32 -> WT[N][K] bf16 ----------------
__global__ __launch_bounds__(256) void transpose_cvt_w(const float* __restrict__ W,
                                                       u16* __restrict__ WT) {
  __shared__ u16 t[64][65];
  const int k0 = blockIdx.x * 64, n0 = blockIdx.y * 64;
  const int tid = threadIdx.x;
  const int r = tid >> 4;          // 0..15
  const int c4 = (tid & 15) * 4;   // col group
#pragma unroll
  for (int it = 0; it < 4; ++it) {
    int k = r + it * 16;
    float4 v = *(const float4*)&W[(size_t)(k0 + k) * DDIM + n0 + c4];
    t[c4 + 0][k] = f2bf(v.x);
    t[c4 + 1][k] = f2bf(v.y);
    t[c4 + 2][k] = f2bf(v.z);
    t[c4 + 3][k] = f2bf(v.w);
  }
  __syncthreads();
#pragma unroll
  for (int it = 0; it < 4; ++it) {
    int n = r + it * 16;
    uint2 o;
    u16* po = (u16*)&o;
#pragma unroll
    for (int j = 0; j < 4; ++j) po[j] = t[n][c4 + j];
    *(uint2*)&WT[(size_t)(n0 + n) * DDIM + k0 + c4] = o;
  }
}

// ---------------- Vp (B,S,D) bf16 -> VpT (B*H, HD, S) bf16 ----------------
__global__ __launch_bounds__(256) void transpose_v(const u16* __restrict__ Vp,
                                                   u16* __restrict__ VpT) {
  __shared__ u16 t[64][65];
  const int bh = blockIdx.y, b = bh >> 4, h = bh & 15;
  const int s0 = blockIdx.x * 64;
  const int tid = threadIdx.x;
  const int r = tid >> 3;        // 0..31
  const int c8 = (tid & 7) * 8;  // 8-elem chunk
  const u16* src = Vp + ((size_t)(b * SS + s0)) * DDIM + h * 64;
#pragma unroll
  for (int it = 0; it < 2; ++it) {
    int s = r + it * 32;
    int4 v = *(const int4*)(src + (size_t)s * DDIM + c8);
    u16* pv = (u16*)&v;
#pragma unroll
    for (int j = 0; j < 8; ++j) t[c8 + j][s] = pv[j];
  }
  __syncthreads();
  u16* dst = VpT + (size_t)bh * 64 * SS + s0;
#pragma unroll
  for (int it = 0; it < 2; ++it) {
    int d = r + it * 32;
    int4 o;
    u16* po = (u16*)&o;
#pragma unroll
    for (int j = 0; j < 8; ++j) po[j] = t[d][c8 + j];
    *(int4*)(dst + (size_t)d * SS + c8) = o;
  }
}

// ---------------- GEMM: 128x128 tile, BK=64, 2-phase double-buffer ----------
// MODE 0: fused QKV. A = Abase + sel*4M (sel = colB0>>10), BT spans 3072 rows,
//         bias b0/b1/b2 by sel, bf16 out to C + sel*4M, Q (sel 0) scaled 1/8.
// MODE 1: plain, f32 out, bias b0.
template <int MODE>
__global__ __launch_bounds__(256) void gemm_bt(const u16* __restrict__ Abase,
                                               const u16* __restrict__ BT,
                                               const float* __restrict__ b0,
                                               const float* __restrict__ b1,
                                               const float* __restrict__ b2,
                                               void* __restrict__ C) {
  __shared__ __align__(16) u16 Al[2][128][64];
  __shared__ __align__(16) u16 Bl[2][128][64];
  const int tid = threadIdx.x;
  const int wid = tid >> 6, lane = tid & 63;
  const int wm = (wid >> 1) * 64, wn = (wid & 1) * 64;
  const int rowA0 = blockIdx.x * 128, colB0 = blockIdx.y * 128;
  const int sel = (MODE == 0) ? (colB0 >> 10) : 0;
  const u16* Ag = Abase + (size_t)sel * ((size_t)MROWS * DDIM) + (size_t)rowA0 * DDIM;
  const u16* Bg = BT + (size_t)colB0 * DDIM;
  f32x4 acc[4][4] = {};
  const int rl = lane >> 3;        // 0..7
  const int ce = (lane & 7) * 8;   // chunk offset (elems)

#define G_STAGE(buf, kt)                                                       \
  do {                                                                         \
    _Pragma("unroll") for (int c = 0; c < 4; ++c) {                            \
      int rt = wid * 32 + c * 8;                                               \
      __builtin_amdgcn_global_load_lds(                                        \
          (GASV*)(Ag + (size_t)(rt + rl) * DDIM + (kt) + ce),                  \
          (LASV*)((char*)&Al[buf][0][0] + rt * 128), 16, 0, 0);                \
      __builtin_amdgcn_global_load_lds(                                        \
          (GASV*)(Bg + (size_t)(rt + rl) * DDIM + (kt) + ce),                  \
          (LASV*)((char*)&Bl[buf][0][0] + rt * 128), 16, 0, 0);                \
    }                                                                          \
  } while (0)

  G_STAGE(0, 0);
  __syncthreads();
  for (int t = 0; t < 16; ++t) {  // K = 1024 = 16 * 64
    const int cur = t & 1;
    if (t < 15) G_STAGE(cur ^ 1, (t + 1) * 64);
#pragma unroll
    for (int kk = 0; kk < 64; kk += 32) {
      bf16x8 af[4], bfr[4];
#pragma unroll
      for (int i = 0; i < 4; ++i)
        af[i] = *(const bf16x8*)&Al[cur][wm + i * 16 + (lane & 15)][kk + (lane >> 4) * 8];
#pragma unroll
      for (int j = 0; j < 4; ++j)
        bfr[j] = *(const bf16x8*)&Bl[cur][wn + j * 16 + (lane & 15)][kk + (lane >> 4) * 8];
#pragma unroll
      for (int i = 0; i < 4; ++i)
#pragma unroll
        for (int j = 0; j < 4; ++j)
          acc[i][j] = __builtin_amdgcn_mfma_f32_16x16x32_bf16(af[i], bfr[j], acc[i][j], 0, 0, 0);
    }
    __syncthreads();
  }
#undef G_STAGE

  if (MODE == 0) {
    const float* bp = (sel == 0) ? b0 : (sel == 1 ? b1 : b2);
    const float scale = (sel == 0) ? 0.125f : 1.0f;  // fold 1/sqrt(HD) into Q
    u16* dst = (u16*)C + (size_t)sel * ((size_t)MROWS * DDIM);
    const int colw0 = (colB0 & 1023) + wn;
#pragma unroll
    for (int i = 0; i < 4; ++i)
#pragma unroll
      for (int j = 0; j < 4; ++j) {
        int colw = colw0 + j * 16 + (lane & 15);
        float bv = bp[colw];
#pragma unroll
        for (int r = 0; r < 4; ++r) {
          int row = rowA0 + wm + i * 16 + (lane >> 4) * 4 + r;
          dst[(size_t)row * DDIM + colw] = f2bf((acc[i][j][r] + bv) * scale);
        }
      }
  } else {
#pragma unroll
    for (int i = 0; i < 4; ++i)
#pragma unroll
      for (int j = 0; j < 4; ++j) {
        int col = colB0 + wn + j * 16 + (lane & 15);
        float bv = b0[col];
#pragma unroll
        for (int r = 0; r < 4; ++r) {
          int row = rowA0 + wm + i * 16 + (lane >> 4) * 4 + r;
          ((float*)C)[(size_t)row * DDIM + col] = acc[i][j][r] + bv;
        }
      }
  }
}

// ---------------- Flash attention ----------------
// grid: (S/64 q-tiles, B*H). 4 waves; wave w owns q-rows [w*16, w*16+16).
// K/V LDS tiles XOR-swizzled (chunk ^= row&7) via pre-swizzled global source;
// 2-phase double-buffered prefetch; mask via packed bitmask.
__global__ __launch_bounds__(256) void attn_fwd(const u16* __restrict__ Qp,
                                                const u16* __restrict__ Kp,
                                                const u16* __restrict__ VpT,
                                                const u64* __restrict__ Mbits,
                                                u16* __restrict__ O) {
  __shared__ __align__(16) u16 Kl[2][64][64];  // [buf][kv][d], swizzled
  __shared__ __align__(16) u16 Vl[2][64][64];  // [buf][d][kv], swizzled
  __shared__ __align__(16) u16 Pl[4][16][64];  // per-wave P, swizzled
  const int tid = threadIdx.x, wid = tid >> 6, lane = tid & 63;
  const int bh = blockIdx.y, b = bh >> 4, h = bh & 15;
  const int q0 = blockIdx.x * 64;
  const int hi = lane >> 4, cbase = lane & 15, rbase = hi * 4;
  const int lx = lane & 7;  // XOR key for swizzled reads (row&7 == lane&7 here)

  bf16x8 qf[2];
  {
    const u16* qb = Qp + (size_t)(b * SS + q0 + wid * 16 + cbase) * DDIM + h * 64 + hi * 8;
    qf[0] = *(const bf16x8*)qb;
    qf[1] = *(const bf16x8*)(qb + 32);
  }
  float m_run[4], l_run[4];
  f32x4 accO[4];
#pragma unroll
  for (int j = 0; j < 4; ++j) { m_run[j] = -__builtin_inff(); l_run[j] = 0.f; }
#pragma unroll
  for (int f = 0; f < 4; ++f) accO[f] = (f32x4){0.f, 0.f, 0.f, 0.f};

  const u16* Kgb = Kp + (size_t)b * SS * DDIM + h * 64;
  const u16* Vgb = VpT + (size_t)bh * 64 * SS;
  const u64* Mb = Mbits + (size_t)(b * SS + q0 + wid * 16) * (SS / 64);
  const int rl = lane >> 3;
  const int ceS = ((lane & 7) ^ rl) * 8;  // pre-swizzled source chunk

#define STAGE_KV(buf, kv)                                                      \
  do {                                                                         \
    _Pragma("unroll") for (int c = 0; c < 2; ++c) {                            \
      int rt = wid * 16 + c * 8;                                               \
      __builtin_amdgcn_global_load_lds(                                        \
          (GASV*)(Kgb + (size_t)((kv) + rt + rl) * DDIM + ceS),                \
          (LASV*)((char*)&Kl[buf][0][0] + rt * 128), 16, 0, 0);                \
      __builtin_amdgcn_global_load_lds(                                        \
          (GASV*)(Vgb + (size_t)(rt + rl) * SS + (kv) + ceS),                  \
          (LASV*)((char*)&Vl[buf][0][0] + rt * 128), 16, 0, 0);                \
    }                                                                          \
  } while (0)

  STAGE_KV(0, 0);
  __syncthreads();

  for (int t = 0; t < SS / 64; ++t) {
    const int kv0 = t * 64, cur = t & 1;
    // mask words FIRST (so their vmcnt wait doesn't drain the prefetch)
    u64 mb[4];
#pragma unroll
    for (int j = 0; j < 4; ++j) mb[j] = Mb[(rbase + j) * (SS / 64) + (kv0 >> 6)];
    if (t < SS / 64 - 1) STAGE_KV(cur ^ 1, kv0 + 64);

    // scores: S[q][kv] = sum_d Q[q][d] K[kv][d]  (Q pre-scaled by 1/8)
    f32x4 sc[4];
    __builtin_amdgcn_s_setprio(1);
#pragma unroll
    for (int fn = 0; fn < 4; ++fn) {
      f32x4 c = (f32x4){0.f, 0.f, 0.f, 0.f};
#pragma unroll
      for (int ks = 0; ks < 2; ++ks) {
        bf16x8 kf = *(const bf16x8*)&Kl[cur][fn * 16 + cbase][((ks * 4 + hi) ^ lx) * 8];
        c = __builtin_amdgcn_mfma_f32_16x16x32_bf16(qf[ks], kf, c, 0, 0, 0);
      }
      sc[fn] = c;
    }
    __builtin_amdgcn_s_setprio(0);

#pragma unroll
    for (int fn = 0; fn < 4; ++fn)
#pragma unroll
      for (int j = 0; j < 4; ++j) {
        float s = sc[fn][j];
        if (((unsigned)(mb[j] >> (fn * 16)) >> cbase) & 1) s = -__builtin_inff();
        sc[fn][j] = s;
      }
    // online softmax (per q-row; 16-lane group reduce)
    float bmax[4];
#pragma unroll
    for (int j = 0; j < 4; ++j)
      bmax[j] = fmaxf(fmaxf(sc[0][j], sc[1][j]), fmaxf(sc[2][j], sc[3][j]));
#pragma unroll
    for (int off = 1; off < 16; off <<= 1)
#pragma unroll
      for (int j = 0; j < 4; ++j) bmax[j] = fmaxf(bmax[j], __shfl_xor(bmax[j], off, 64));
    float alpha[4];
#pragma unroll
    for (int j = 0; j < 4; ++j) {
      float mn = fmaxf(m_run[j], bmax[j]);
      alpha[j] = (m_run[j] == mn) ? 1.0f : __expf(m_run[j] - mn);  // -inf==-inf -> 1
      m_run[j] = mn;
    }
    float rsum[4] = {0.f, 0.f, 0.f, 0.f};
#pragma unroll
    for (int fn = 0; fn < 4; ++fn)
#pragma unroll
      for (int j = 0; j < 4; ++j) {
        float s = sc[fn][j];
        float p = (s == -__builtin_inff()) ? 0.f : __expf(s - m_run[j]);
        sc[fn][j] = p;
        rsum[j] += p;
      }
#pragma unroll
    for (int off = 1; off < 16; off <<= 1)
#pragma unroll
      for (int j = 0; j < 4; ++j) rsum[j] += __shfl_xor(rsum[j], off, 64);
#pragma unroll
    for (int j = 0; j < 4; ++j) l_run[j] = l_run[j] * alpha[j] + rsum[j];
#pragma unroll
    for (int f = 0; f < 4; ++f)
#pragma unroll
      for (int j = 0; j < 4; ++j) accO[f][j] *= alpha[j];

    // P -> LDS (bf16, swizzled), then PV: O[q][d] += P[q][kv] V[kv][d]
#pragma unroll
    for (int fn = 0; fn < 4; ++fn)
#pragma unroll
      for (int j = 0; j < 4; ++j) {
        int row = rbase + j, col = fn * 16 + cbase;
        Pl[wid][row][(((col >> 3) ^ (row & 7)) << 3) | (col & 7)] = f2bf(sc[fn][j]);
      }
    bf16x8 pf0 = *(const bf16x8*)&Pl[wid][cbase][(hi ^ lx) * 8];
    bf16x8 pf1 = *(const bf16x8*)&Pl[wid][cbase][((4 + hi) ^ lx) * 8];
    __builtin_amdgcn_s_setprio(1);
#pragma unroll
    for (int nd = 0; nd < 4; ++nd) {
      bf16x8 v0 = *(const bf16x8*)&Vl[cur][nd * 16 + cbase][(hi ^ lx) * 8];
      bf16x8 v1 = *(const bf16x8*)&Vl[cur][nd * 16 + cbase][((4 + hi) ^ lx) * 8];
      accO[nd] = __builtin_amdgcn_mfma_f32_16x16x32_bf16(pf0, v0, accO[nd], 0, 0, 0);
      accO[nd] = __builtin_amdgcn_mfma_f32_16x16x32_bf16(pf1, v1, accO[nd], 0, 0, 0);
    }
    __builtin_amdgcn_s_setprio(0);
    __syncthreads();  // drains prefetch vmcnt + joins waves
  }
#undef STAGE_KV

#pragma unroll
  for (int nd = 0; nd < 4; ++nd)
#pragma unroll
    for (int j = 0; j < 4; ++j) {
      int row = q0 + wid * 16 + hi * 4 + j;
      int col = h * 64 + nd * 16 + cbase;
      O[(size_t)(b * SS + row) * DDIM + col] = f2bf(accO[nd][j] / l_run[j]);
    }
}

// ---------------- residual + LayerNorm (ddof=1, std+eps) ----------------
__global__ __launch_bounds__(256) void ln_res(const float* __restrict__ qin,
                                              const float* __restrict__ proj,
                                              const float* __restrict__ gamma,
                                              const float* __restrict__ beta,
                                              float* __restrict__ out) {
  const int row = blockIdx.x, tid = threadIdx.x;
  const size_t base = (size_t)row * DDIM + tid * 4;
  float4 a = *(const float4*)(qin + base);
  float4 p = *(const float4*)(proj + base);
  float x0 = a.x + p.x, x1 = a.y + p.y, x2 = a.z + p.z, x3 = a.w + p.w;
  float s = x0 + x1 + x2 + x3;
  __shared__ float red[4];
#pragma unroll
  for (int off = 32; off >= 1; off >>= 1) s += __shfl_xor(s, off, 64);
  const int wid = tid >> 6, lane = tid & 63;
  if (lane == 0) red[wid] = s;
  __syncthreads();
  float mean = (red[0] + red[1] + red[2] + red[3]) * (1.0f / DDIM);
  float d0 = x0 - mean, d1 = x1 - mean, d2 = x2 - mean, d3 = x3 - mean;
  float ss = d0 * d0 + d1 * d1 + d2 * d2 + d3 * d3;
#pragma unroll
  for (int off = 32; off >= 1; off >>= 1) ss += __shfl_xor(ss, off, 64);
  __syncthreads();
  if (lane == 0) red[wid] = ss;
  __syncthreads();
  float var = (red[0] + red[1] + red[2] + red[3]) * (1.0f / (DDIM - 1));
  float denom = sqrtf(var) + 1e-6f;
  float4 g = *(const float4*)(gamma + (size_t)tid * 4);
  float4 be = *(const float4*)(beta + (size_t)tid * 4);
  float4 o;
  o.x = g.x * d0 / denom + be.x;
  o.y = g.y * d1 / denom + be.y;
  o.z = g.z * d2 / denom + be.z;
  o.w = g.w * d3 / denom + be.w;
  *(float4*)(out + base) = o;
}

extern "C" void kernel_launch(void* const* d_in, const int* in_sizes, int n_in,
                              void* d_out, int out_size, void* d_ws, size_t ws_size,
                              hipStream_t stream) {
  const float* query = (const float*)d_in[0];
  const float* key = (const float*)d_in[1];
  const float* value = (const float*)d_in[2];
  const int* mask = (const int*)d_in[3];  // bool passed as int32
  const float* Wq = (const float*)d_in[4];
  const float* bq = (const float*)d_in[5];
  const float* Wk = (const float*)d_in[6];
  const float* bk = (const float*)d_in[7];
  const float* Wv = (const float*)d_in[8];
  const float* bv = (const float*)d_in[9];
  const float* Wo = (const float*)d_in[10];
  const float* bo = (const float*)d_in[11];
  const float* gamma = (const float*)d_in[12];
  const float* beta = (const float*)d_in[13];
  float* out = (float*)d_out;
  char* ws = (char*)d_ws;
  const size_t MB = 1ull << 20;
  // Workspace map (64 MB):
  u16* qb = (u16*)(ws + 0 * MB);    // 8MB; dead after QKV-GEMM -> maskbits
  u16* kb = (u16*)(ws + 8 * MB);    // 8MB; dead after QKV-GEMM -> proj
  u16* vb = (u16*)(ws + 16 * MB);   // 8MB; dead after QKV-GEMM -> VpT
  u16* WqT = (u16*)(ws + 24 * MB);  // WqT/WkT/WvT contiguous = [3072][1024]
  u16* WkT = (u16*)(ws + 26 * MB);
  u16* WvT = (u16*)(ws + 28 * MB);
  u16* WoT = (u16*)(ws + 30 * MB);
  u16* Qp = (u16*)(ws + 32 * MB);   // Qp/Kp/Vp contiguous (8MB stride)
  u16* Kp = (u16*)(ws + 40 * MB);
  u16* Vp = (u16*)(ws + 48 * MB);
  u16* VpT = (u16*)(ws + 16 * MB);  // over vb
  u16* attnb = (u16*)(ws + 56 * MB); // 8MB
  u64* maskbits = (u64*)(ws + 0 * MB);   // 1MB over qb (after QKV-GEMM)
  float* proj = (float*)(ws + 8 * MB);   // 16MB over kb+vb/VpT (after attn)

  const int NELEM = MROWS * DDIM;  // 4M
  cvt_bf16_k<<<NELEM / 1024, 256, 0, stream>>>(query, qb);
  cvt_bf16_k<<<NELEM / 1024, 256, 0, stream>>>(key, kb);
  cvt_bf16_k<<<NELEM / 1024, 256, 0, stream>>>(value, vb);
  transpose_cvt_w<<<dim3(16, 16), 256, 0, stream>>>(Wq, WqT);
  transpose_cvt_w<<<dim3(16, 16), 256, 0, stream>>>(Wk, WkT);
  transpose_cvt_w<<<dim3(16, 16), 256, 0, stream>>>(Wv, WvT);
  transpose_cvt_w<<<dim3(16, 16), 256, 0, stream>>>(Wo, WoT);
  // fused QKV projection: A-select and out-select by colB0>>10
  gemm_bt<0><<<dim3(MROWS / 128, 3 * DDIM / 128), 256, 0, stream>>>(
      qb, WqT, bq, bk, bv, Qp);
  // mask bitpack after QKV-GEMM (qb region dead)
  cvt_mask_bits<<<(NB * SS * SS) / 256, 256, 0, stream>>>(mask, maskbits);
  transpose_v<<<dim3(SS / 64, NB * NH), 256, 0, stream>>>(Vp, VpT);
  attn_fwd<<<dim3(SS / 64, NB * NH), 256, 0, stream>>>(Qp, Kp, VpT, maskbits, attnb);
  gemm_bt<1><<<dim3(MROWS / 128, DDIM / 128), 256, 0, stream>>>(
      attnb, WoT, bo, nullptr, nullptr, proj);
  ln_res<<<MROWS, 256, 0, stream>>>(query, proj, gamma, beta, out);
}

// Round 5
// 217.249 us; speedup vs baseline: 1.4609x; 1.3199x over previous
//
#include <hip/hip_runtime.h>

// MultiHeadAttn fused pipeline for MI355X (gfx950).
// B=2, S=2048, D=1024, H=16, HD=64. Round 5:
//  attn rewritten with swapped QK^T (mfma(K,Q)) so each lane owns one q-row:
//  scalar m/l, 2-shuffle row reduce, exp2-domain softmax (log2e folded into
//  Q prescale), defer-max (THR=8), packed P via v_cvt_pk_bf16_f32 +
//  ds_write_b64, per-lane u64 mask, bijective XCD swizzle for K/V locality.

#define NB 2
#define SS 2048
#define DDIM 1024
#define NH 16
#define HDIM 64
#define MROWS (NB * SS)  // 4096

typedef unsigned short u16;
typedef unsigned long long u64;
typedef unsigned int u32;
typedef short bf16x8 __attribute__((ext_vector_type(8)));
typedef float f32x4 __attribute__((ext_vector_type(4)));

typedef const __attribute__((address_space(1))) void GASV;
typedef __attribute__((address_space(3))) void LASV;

#if __has_builtin(__builtin_amdgcn_exp2f)
#define EXP2F __builtin_amdgcn_exp2f
#else
#define EXP2F exp2f
#endif

__device__ __forceinline__ u16 f2bf(float f) {
  unsigned u = __builtin_bit_cast(unsigned, f);
  u += 0x7FFFu + ((u >> 16) & 1u);  // RNE; inputs finite
  return (u16)(u >> 16);
}

__device__ __forceinline__ u32 cvt_pk_bf16(float a, float b) {
  u32 d;  // D[15:0]=bf16(a), D[31:16]=bf16(b)
  asm("v_cvt_pk_bf16_f32 %0, %1, %2" : "=v"(d) : "v"(a), "v"(b));
  return d;
}

// ---------------- f32 -> bf16 elementwise ----------------
__global__ __launch_bounds__(256) void cvt_bf16_k(const float* __restrict__ in,
                                                  u16* __restrict__ out) {
  size_t i = ((size_t)blockIdx.x * 256 + threadIdx.x) * 4;
  float4 v = *(const float4*)(in + i);
  uint2 o;
  u16* po = (u16*)&o;
  po[0] = f2bf(v.x); po[1] = f2bf(v.y); po[2] = f2bf(v.z); po[3] = f2bf(v.w);
  *(uint2*)(out + i) = o;
}

// ---------------- mask int32 -> bitmask (64 kv per u64 word) ----------------
__global__ __launch_bounds__(256) void cvt_mask_bits(const int* __restrict__ in,
                                                     u64* __restrict__ out) {
  size_t w = ((size_t)blockIdx.x * 256 + threadIdx.x) >> 6;
  int lane = threadIdx.x & 63;
  int v = in[w * 64 + lane];
  u64 bits = __ballot(v != 0);  // bit l = (mask[w*64+l] != 0)
  if (lane == 0) out[w] = bits;
}

// ---------------- W[K][N] f32 -> WT[N][K] bf16 ----------------
__global__ __launch_bounds__(256) void transpose_cvt_w(const float* __restrict__ W,
                                                       u16* __restrict__ WT) {
  __shared__ u16 t[64][65];
  const int k0 = blockIdx.x * 64, n0 = blockIdx.y * 64;
  const int tid = threadIdx.x;
  const int r = tid >> 4;          // 0..15
  const int c4 = (tid & 15) * 4;   // col group
#pragma unroll
  for (int it = 0; it < 4; ++it) {
    int k = r + it * 16;
    float4 v = *(const float4*)&W[(size_t)(k0 + k) * DDIM + n0 + c4];
    t[c4 + 0][k] = f2bf(v.x);
    t[c4 + 1][k] = f2bf(v.y);
    t[c4 + 2][k] = f2bf(v.z);
    t[c4 + 3][k] = f2bf(v.w);
  }
  __syncthreads();
#pragma unroll
  for (int it = 0; it < 4; ++it) {
    int n = r + it * 16;
    uint2 o;
    u16* po = (u16*)&o;
#pragma unroll
    for (int j = 0; j < 4; ++j) po[j] = t[n][c4 + j];
    *(uint2*)&WT[(size_t)(n0 + n) * DDIM + k0 + c4] = o;
  }
}

// ---------------- Vp (B,S,D) bf16 -> VpT (B*H, HD, S) bf16 ----------------
__global__ __launch_bounds__(256) void transpose_v(const u16* __restrict__ Vp,
                                                   u16* __restrict__ VpT) {
  __shared__ u16 t[64][65];
  const int bh = blockIdx.y, b = bh >> 4, h = bh & 15;
  const int s0 = blockIdx.x * 64;
  const int tid = threadIdx.x;
  const int r = tid >> 3;        // 0..31
  const int c8 = (tid & 7) * 8;  // 8-elem chunk
  const u16* src = Vp + ((size_t)(b * SS + s0)) * DDIM + h * 64;
#pragma unroll
  for (int it = 0; it < 2; ++it) {
    int s = r + it * 32;
    int4 v = *(const int4*)(src + (size_t)s * DDIM + c8);
    u16* pv = (u16*)&v;
#pragma unroll
    for (int j = 0; j < 8; ++j) t[c8 + j][s] = pv[j];
  }
  __syncthreads();
  u16* dst = VpT + (size_t)bh * 64 * SS + s0;
#pragma unroll
  for (int it = 0; it < 2; ++it) {
    int d = r + it * 32;
    int4 o;
    u16* po = (u16*)&o;
#pragma unroll
    for (int j = 0; j < 8; ++j) po[j] = t[d][c8 + j];
    *(int4*)(dst + (size_t)d * SS + c8) = o;
  }
}

// ---------------- GEMM: 128x128 tile, BK=64, 2-phase double-buffer ----------
// MODE 0: fused QKV. A = Abase + sel*4M (sel = colB0>>10), BT spans 3072 rows,
//         bias b0/b1/b2 by sel, bf16 out to C + sel*4M.
//         Q (sel 0) scaled by 0.125*log2(e) (exp2-domain softmax).
// MODE 1: plain, f32 out, bias b0.
template <int MODE>
__global__ __launch_bounds__(256) void gemm_bt(const u16* __restrict__ Abase,
                                               const u16* __restrict__ BT,
                                               const float* __restrict__ b0,
                                               const float* __restrict__ b1,
                                               const float* __restrict__ b2,
                                               void* __restrict__ C) {
  __shared__ __align__(16) u16 Al[2][128][64];
  __shared__ __align__(16) u16 Bl[2][128][64];
  const int tid = threadIdx.x;
  const int wid = tid >> 6, lane = tid & 63;
  const int wm = (wid >> 1) * 64, wn = (wid & 1) * 64;
  const int rowA0 = blockIdx.x * 128, colB0 = blockIdx.y * 128;
  const int sel = (MODE == 0) ? (colB0 >> 10) : 0;
  const u16* Ag = Abase + (size_t)sel * ((size_t)MROWS * DDIM) + (size_t)rowA0 * DDIM;
  const u16* Bg = BT + (size_t)colB0 * DDIM;
  f32x4 acc[4][4] = {};
  const int rl = lane >> 3;        // 0..7
  const int ce = (lane & 7) * 8;   // chunk offset (elems)

#define G_STAGE(buf, kt)                                                       \
  do {                                                                         \
    _Pragma("unroll") for (int c = 0; c < 4; ++c) {                            \
      int rt = wid * 32 + c * 8;                                               \
      __builtin_amdgcn_global_load_lds(                                        \
          (GASV*)(Ag + (size_t)(rt + rl) * DDIM + (kt) + ce),                  \
          (LASV*)((char*)&Al[buf][0][0] + rt * 128), 16, 0, 0);                \
      __builtin_amdgcn_global_load_lds(                                        \
          (GASV*)(Bg + (size_t)(rt + rl) * DDIM + (kt) + ce),                  \
          (LASV*)((char*)&Bl[buf][0][0] + rt * 128), 16, 0, 0);                \
    }                                                                          \
  } while (0)

  G_STAGE(0, 0);
  __syncthreads();
  for (int t = 0; t < 16; ++t) {  // K = 1024 = 16 * 64
    const int cur = t & 1;
    if (t < 15) G_STAGE(cur ^ 1, (t + 1) * 64);
#pragma unroll
    for (int kk = 0; kk < 64; kk += 32) {
      bf16x8 af[4], bfr[4];
#pragma unroll
      for (int i = 0; i < 4; ++i)
        af[i] = *(const bf16x8*)&Al[cur][wm + i * 16 + (lane & 15)][kk + (lane >> 4) * 8];
#pragma unroll
      for (int j = 0; j < 4; ++j)
        bfr[j] = *(const bf16x8*)&Bl[cur][wn + j * 16 + (lane & 15)][kk + (lane >> 4) * 8];
#pragma unroll
      for (int i = 0; i < 4; ++i)
#pragma unroll
        for (int j = 0; j < 4; ++j)
          acc[i][j] = __builtin_amdgcn_mfma_f32_16x16x32_bf16(af[i], bfr[j], acc[i][j], 0, 0, 0);
    }
    __syncthreads();
  }
#undef G_STAGE

  if (MODE == 0) {
    const float* bp = (sel == 0) ? b0 : (sel == 1 ? b1 : b2);
    // fold 1/sqrt(HD) and log2(e) into Q (softmax runs in exp2 domain)
    const float scale = (sel == 0) ? 0.125f * 1.44269504088896340736f : 1.0f;
    u16* dst = (u16*)C + (size_t)sel * ((size_t)MROWS * DDIM);
    const int colw0 = (colB0 & 1023) + wn;
#pragma unroll
    for (int i = 0; i < 4; ++i)
#pragma unroll
      for (int j = 0; j < 4; ++j) {
        int colw = colw0 + j * 16 + (lane & 15);
        float bv = bp[colw];
#pragma unroll
        for (int r = 0; r < 4; ++r) {
          int row = rowA0 + wm + i * 16 + (lane >> 4) * 4 + r;
          dst[(size_t)row * DDIM + colw] = f2bf((acc[i][j][r] + bv) * scale);
        }
      }
  } else {
#pragma unroll
    for (int i = 0; i < 4; ++i)
#pragma unroll
      for (int j = 0; j < 4; ++j) {
        int col = colB0 + wn + j * 16 + (lane & 15);
        float bv = b0[col];
#pragma unroll
        for (int r = 0; r < 4; ++r) {
          int row = rowA0 + wm + i * 16 + (lane >> 4) * 4 + r;
          ((float*)C)[(size_t)row * DDIM + col] = acc[i][j][r] + bv;
        }
      }
  }
}

// ---------------- Flash attention (swapped QK^T, per-lane q-row) ------------
// grid: 1024 blocks (XCD-swizzled). 4 waves; wave w owns q-rows [w*16,w*16+16).
// Lane (cbase=lane&15, hi=lane>>4): owns softmax state for q=cbase; score
// fragments sc[fn][j] = S[q=cbase][kv=fn*16+hi*4+j] in exp2 domain.
__global__ __launch_bounds__(256) void attn_fwd(const u16* __restrict__ Qp,
                                                const u16* __restrict__ Kp,
                                                const u16* __restrict__ VpT,
                                                const u64* __restrict__ Mbits,
                                                u16* __restrict__ O) {
  __shared__ __align__(16) u16 Kl[2][64][64];  // [buf][kv][d], swizzled
  __shared__ __align__(16) u16 Vl[2][64][64];  // [buf][d][kv], swizzled
  __shared__ __align__(16) u16 Pl[4][16][64];  // per-wave P [q][kv], swizzled
  const int tid = threadIdx.x, wid = tid >> 6, lane = tid & 63;
  // XCD swizzle: 8 XCDs x (4 bh x 32 q-tiles) -> K/V of a head stays on 1 XCD
  const int bid = blockIdx.x;
  const int bh = (bid & 7) * 4 + ((bid >> 3) & 3);
  const int q0 = (bid >> 5) * 64;
  const int b = bh >> 4, h = bh & 15;
  const int hi = lane >> 4, cbase = lane & 15, lx = lane & 7;  // lx == cbase&7

  bf16x8 qf[2];
  {
    const u16* qb = Qp + (size_t)(b * SS + q0 + wid * 16 + cbase) * DDIM + h * 64 + hi * 8;
    qf[0] = *(const bf16x8*)qb;
    qf[1] = *(const bf16x8*)(qb + 32);
  }
  float m_run = -1e30f, l_run = 0.f;
  f32x4 accO[4];
#pragma unroll
  for (int f = 0; f < 4; ++f) accO[f] = (f32x4){0.f, 0.f, 0.f, 0.f};

  const u16* Kgb = Kp + (size_t)b * SS * DDIM + h * 64;
  const u16* Vgb = VpT + (size_t)bh * 64 * SS;
  const u64* Mb = Mbits + (size_t)(b * SS + q0 + wid * 16 + cbase) * (SS / 64);
  const int rl = lane >> 3;
  const int ceS = ((lane & 7) ^ rl) * 8;  // pre-swizzled source chunk

#define STAGE_KV(buf, kv)                                                      \
  do {                                                                         \
    _Pragma("unroll") for (int c = 0; c < 2; ++c) {                            \
      int rt = wid * 16 + c * 8;                                               \
      __builtin_amdgcn_global_load_lds(                                        \
          (GASV*)(Kgb + (size_t)((kv) + rt + rl) * DDIM + ceS),                \
          (LASV*)((char*)&Kl[buf][0][0] + rt * 128), 16, 0, 0);                \
      __builtin_amdgcn_global_load_lds(                                        \
          (GASV*)(Vgb + (size_t)(rt + rl) * SS + (kv) + ceS),                  \
          (LASV*)((char*)&Vl[buf][0][0] + rt * 128), 16, 0, 0);                \
    }                                                                          \
  } while (0)

  STAGE_KV(0, 0);
  __syncthreads();

  for (int t = 0; t < SS / 64; ++t) {
    const int cur = t & 1;
    // mask word FIRST (ordered before stage loads: its wait won't drain them)
    u64 mrow = Mb[t];
    if (t < SS / 64 - 1) STAGE_KV(cur ^ 1, (t + 1) * 64);

    // scores (swapped): sc[fn] = mfma(K_frag_fn, Q) -> D[kv][q], col=q=cbase
    f32x4 sc[4];
    __builtin_amdgcn_s_setprio(1);
#pragma unroll
    for (int fn = 0; fn < 4; ++fn) {
      f32x4 c = (f32x4){0.f, 0.f, 0.f, 0.f};
#pragma unroll
      for (int ks = 0; ks < 2; ++ks) {
        bf16x8 kf = *(const bf16x8*)&Kl[cur][fn * 16 + cbase][((ks * 4 + hi) ^ lx) * 8];
        c = __builtin_amdgcn_mfma_f32_16x16x32_bf16(kf, qf[ks], c, 0, 0, 0);
      }
      sc[fn] = c;
    }
    __builtin_amdgcn_s_setprio(0);

    // mask: bit kv of mrow, kv = fn*16 + hi*4 + j
    {
      u32 wlo = (u32)(mrow >> (hi * 4));
      u32 whi = (u32)(mrow >> (hi * 4 + 32));
#pragma unroll
      for (int fn = 0; fn < 4; ++fn)
#pragma unroll
        for (int j = 0; j < 4; ++j)
          if ((((fn < 2) ? wlo : whi) >> ((fn & 1) * 16 + j)) & 1)
            sc[fn][j] = -__builtin_inff();
    }
    // row max: 15 in-reg + 2 shuffles (lanes hi=0..3 share q=cbase)
    float pmax;
    {
      float a = fmaxf(fmaxf(sc[0][0], sc[0][1]), fmaxf(sc[0][2], sc[0][3]));
      float bm = fmaxf(fmaxf(sc[1][0], sc[1][1]), fmaxf(sc[1][2], sc[1][3]));
      float c = fmaxf(fmaxf(sc[2][0], sc[2][1]), fmaxf(sc[2][2], sc[2][3]));
      float d = fmaxf(fmaxf(sc[3][0], sc[3][1]), fmaxf(sc[3][2], sc[3][3]));
      pmax = fmaxf(fmaxf(a, bm), fmaxf(c, d));
      pmax = fmaxf(pmax, __shfl_xor(pmax, 16, 64));
      pmax = fmaxf(pmax, __shfl_xor(pmax, 32, 64));
    }
    // defer-max: rescale only when max grew by > 8 (p bounded by 2^8)
    if (!__all(pmax <= m_run + 8.f)) {
      float mnew = fmaxf(m_run, pmax);
      float alpha = EXP2F(m_run - mnew);
      m_run = mnew;
      l_run *= alpha;
      float ab[4];
#pragma unroll
      for (int j = 0; j < 4; ++j)
        ab[j] = __shfl(alpha, (lane & 48) + hi * 4 + j, 64);
#pragma unroll
      for (int nd = 0; nd < 4; ++nd)
#pragma unroll
        for (int j = 0; j < 4; ++j) accO[nd][j] *= ab[j];
    }
    // p = exp2(s - m), row sum
    float rsum = 0.f;
#pragma unroll
    for (int fn = 0; fn < 4; ++fn)
#pragma unroll
      for (int j = 0; j < 4; ++j) {
        float p = EXP2F(sc[fn][j] - m_run);
        sc[fn][j] = p;
        rsum += p;
      }
    rsum += __shfl_xor(rsum, 16, 64);
    rsum += __shfl_xor(rsum, 32, 64);
    l_run += rsum;

    // P -> LDS: pack pairs, 4x ds_write_b64 at [q=cbase][kv=fn*16+hi*4]
#pragma unroll
    for (int fn = 0; fn < 4; ++fn) {
      uint2 wpair;
      wpair.x = cvt_pk_bf16(sc[fn][0], sc[fn][1]);
      wpair.y = cvt_pk_bf16(sc[fn][2], sc[fn][3]);
      // chunk = fn*2 + (hi>>1), swizzle chunk ^= cbase&7, sub = (hi&1)*4 u16
      *(uint2*)&Pl[wid][cbase][(((fn * 2 + (hi >> 1)) ^ lx) << 3) + ((hi & 1) << 2)] = wpair;
    }
    bf16x8 pf0 = *(const bf16x8*)&Pl[wid][cbase][(hi ^ lx) * 8];
    bf16x8 pf1 = *(const bf16x8*)&Pl[wid][cbase][((4 + hi) ^ lx) * 8];
    __builtin_amdgcn_s_setprio(1);
#pragma unroll
    for (int nd = 0; nd < 4; ++nd) {
      bf16x8 v0 = *(const bf16x8*)&Vl[cur][nd * 16 + cbase][(hi ^ lx) * 8];
      bf16x8 v1 = *(const bf16x8*)&Vl[cur][nd * 16 + cbase][((4 + hi) ^ lx) * 8];
      accO[nd] = __builtin_amdgcn_mfma_f32_16x16x32_bf16(pf0, v0, accO[nd], 0, 0, 0);
      accO[nd] = __builtin_amdgcn_mfma_f32_16x16x32_bf16(pf1, v1, accO[nd], 0, 0, 0);
    }
    __builtin_amdgcn_s_setprio(0);
    __syncthreads();  // drains prefetch vmcnt + joins waves
  }
#undef STAGE_KV

  // l for output rows q=hi*4+j lives in lane with cbase=hi*4+j
  float lb[4];
#pragma unroll
  for (int j = 0; j < 4; ++j)
    lb[j] = __shfl(l_run, (lane & 48) + hi * 4 + j, 64);
#pragma unroll
  for (int nd = 0; nd < 4; ++nd)
#pragma unroll
    for (int j = 0; j < 4; ++j) {
      int row = q0 + wid * 16 + hi * 4 + j;
      int col = h * 64 + nd * 16 + cbase;
      O[(size_t)(b * SS + row) * DDIM + col] = f2bf(accO[nd][j] / lb[j]);
    }
}

// ---------------- residual + LayerNorm (ddof=1, std+eps) ----------------
__global__ __launch_bounds__(256) void ln_res(const float* __restrict__ qin,
                                              const float* __restrict__ proj,
                                              const float* __restrict__ gamma,
                                              const float* __restrict__ beta,
                                              float* __restrict__ out) {
  const int row = blockIdx.x, tid = threadIdx.x;
  const size_t base = (size_t)row * DDIM + tid * 4;
  float4 a = *(const float4*)(qin + base);
  float4 p = *(const float4*)(proj + base);
  float x0 = a.x + p.x, x1 = a.y + p.y, x2 = a.z + p.z, x3 = a.w + p.w;
  float s = x0 + x1 + x2 + x3;
  __shared__ float red[4];
#pragma unroll
  for (int off = 32; off >= 1; off >>= 1) s += __shfl_xor(s, off, 64);
  const int wid = tid >> 6, lane = tid & 63;
  if (lane == 0) red[wid] = s;
  __syncthreads();
  float mean = (red[0] + red[1] + red[2] + red[3]) * (1.0f / DDIM);
  float d0 = x0 - mean, d1 = x1 - mean, d2 = x2 - mean, d3 = x3 - mean;
  float ss = d0 * d0 + d1 * d1 + d2 * d2 + d3 * d3;
#pragma unroll
  for (int off = 32; off >= 1; off >>= 1) ss += __shfl_xor(ss, off, 64);
  __syncthreads();
  if (lane == 0) red[wid] = ss;
  __syncthreads();
  float var = (red[0] + red[1] + red[2] + red[3]) * (1.0f / (DDIM - 1));
  float denom = sqrtf(var) + 1e-6f;
  float4 g = *(const float4*)(gamma + (size_t)tid * 4);
  float4 be = *(const float4*)(beta + (size_t)tid * 4);
  float4 o;
  o.x = g.x * d0 / denom + be.x;
  o.y = g.y * d1 / denom + be.y;
  o.z = g.z * d2 / denom + be.z;
  o.w = g.w * d3 / denom + be.w;
  *(float4*)(out + base) = o;
}

extern "C" void kernel_launch(void* const* d_in, const int* in_sizes, int n_in,
                              void* d_out, int out_size, void* d_ws, size_t ws_size,
                              hipStream_t stream) {
  const float* query = (const float*)d_in[0];
  const float* key = (const float*)d_in[1];
  const float* value = (const float*)d_in[2];
  const int* mask = (const int*)d_in[3];  // bool passed as int32
  const float* Wq = (const float*)d_in[4];
  const float* bq = (const float*)d_in[5];
  const float* Wk = (const float*)d_in[6];
  const float* bk = (const float*)d_in[7];
  const float* Wv = (const float*)d_in[8];
  const float* bv = (const float*)d_in[9];
  const float* Wo = (const float*)d_in[10];
  const float* bo = (const float*)d_in[11];
  const float* gamma = (const float*)d_in[12];
  const float* beta = (const float*)d_in[13];
  float* out = (float*)d_out;
  char* ws = (char*)d_ws;
  const size_t MB = 1ull << 20;
  // Workspace map (64 MB):
  u16* qb = (u16*)(ws + 0 * MB);    // 8MB; dead after QKV-GEMM -> maskbits
  u16* kb = (u16*)(ws + 8 * MB);    // 8MB; dead after QKV-GEMM -> proj
  u16* vb = (u16*)(ws + 16 * MB);   // 8MB; dead after QKV-GEMM -> VpT
  u16* WqT = (u16*)(ws + 24 * MB);  // WqT/WkT/WvT contiguous = [3072][1024]
  u16* WkT = (u16*)(ws + 26 * MB);
  u16* WvT = (u16*)(ws + 28 * MB);
  u16* WoT = (u16*)(ws + 30 * MB);
  u16* Qp = (u16*)(ws + 32 * MB);   // Qp/Kp/Vp contiguous (8MB stride)
  u16* Kp = (u16*)(ws + 40 * MB);
  u16* Vp = (u16*)(ws + 48 * MB);
  u16* VpT = (u16*)(ws + 16 * MB);  // over vb
  u16* attnb = (u16*)(ws + 56 * MB); // 8MB
  u64* maskbits = (u64*)(ws + 0 * MB);   // 1MB over qb (after QKV-GEMM)
  float* proj = (float*)(ws + 8 * MB);   // 16MB over kb+vb/VpT (after attn)

  const int NELEM = MROWS * DDIM;  // 4M
  cvt_bf16_k<<<NELEM / 1024, 256, 0, stream>>>(query, qb);
  cvt_bf16_k<<<NELEM / 1024, 256, 0, stream>>>(key, kb);
  cvt_bf16_k<<<NELEM / 1024, 256, 0, stream>>>(value, vb);
  transpose_cvt_w<<<dim3(16, 16), 256, 0, stream>>>(Wq, WqT);
  transpose_cvt_w<<<dim3(16, 16), 256, 0, stream>>>(Wk, WkT);
  transpose_cvt_w<<<dim3(16, 16), 256, 0, stream>>>(Wv, WvT);
  transpose_cvt_w<<<dim3(16, 16), 256, 0, stream>>>(Wo, WoT);
  // fused QKV projection: A-select and out-select by colB0>>10
  gemm_bt<0><<<dim3(MROWS / 128, 3 * DDIM / 128), 256, 0, stream>>>(
      qb, WqT, bq, bk, bv, Qp);
  // mask bitpack after QKV-GEMM (qb region dead)
  cvt_mask_bits<<<(NB * SS * SS) / 256, 256, 0, stream>>>(mask, maskbits);
  transpose_v<<<dim3(SS / 64, NB * NH), 256, 0, stream>>>(Vp, VpT);
  attn_fwd<<<1024, 256, 0, stream>>>(Qp, Kp, VpT, maskbits, attnb);
  gemm_bt<1><<<dim3(MROWS / 128, DDIM / 128), 256, 0, stream>>>(
      attnb, WoT, bo, nullptr, nullptr, proj);
  ln_res<<<MROWS, 256, 0, stream>>>(query, proj, gamma, beta, out);
}

// Round 6
// 199.394 us; speedup vs baseline: 1.5917x; 1.0895x over previous
//
#include <hip/hip_runtime.h>

// MultiHeadAttn fused pipeline for MI355X (gfx950).
// B=2, S=2048, D=1024, H=16, HD=64. Round 6:
//  attn VALU-count reduction: launch_bounds(256,4) for addr hoisting,
//  t-loop unrolled x2 (compile-time buffer index, hoisted LDS offsets),
//  mask folded into exp2 arg (p=exp2(fma(bit,-512,s)-m), raw-score max,
//  no -inf corners), single-inst v_exp_f32. Merged small kernels.

#define NB 2
#define SS 2048
#define DDIM 1024
#define NH 16
#define HDIM 64
#define MROWS (NB * SS)  // 4096

typedef unsigned short u16;
typedef unsigned long long u64;
typedef unsigned int u32;
typedef short bf16x8 __attribute__((ext_vector_type(8)));
typedef float f32x4 __attribute__((ext_vector_type(4)));

typedef const __attribute__((address_space(1))) void GASV;
typedef __attribute__((address_space(3))) void LASV;

__device__ __forceinline__ float dev_exp2(float x) {
  float r;
  asm("v_exp_f32 %0, %1" : "=v"(r) : "v"(x));
  return r;
}

__device__ __forceinline__ u16 f2bf(float f) {
  unsigned u = __builtin_bit_cast(unsigned, f);
  u += 0x7FFFu + ((u >> 16) & 1u);  // RNE; inputs finite
  return (u16)(u >> 16);
}

__device__ __forceinline__ u32 cvt_pk_bf16(float a, float b) {
  u32 d;  // D[15:0]=bf16(a), D[31:16]=bf16(b)
  asm("v_cvt_pk_bf16_f32 %0, %1, %2" : "=v"(d) : "v"(a), "v"(b));
  return d;
}

// ---------------- q/k/v f32 -> bf16 (one launch, y selects input) -----------
__global__ __launch_bounds__(256) void cvt_bf16_3(const float* __restrict__ q,
                                                  const float* __restrict__ k,
                                                  const float* __restrict__ v,
                                                  u16* __restrict__ out) {
  const float* in = (blockIdx.y == 0) ? q : (blockIdx.y == 1) ? k : v;
  size_t i = ((size_t)blockIdx.x * 256 + threadIdx.x) * 4;
  float4 val = *(const float4*)(in + i);
  uint2 o;
  u16* po = (u16*)&o;
  po[0] = f2bf(val.x); po[1] = f2bf(val.y); po[2] = f2bf(val.z); po[3] = f2bf(val.w);
  *(uint2*)(out + (size_t)blockIdx.y * MROWS * DDIM + i) = o;
}

// ---------------- mask int32 -> bitmask (64 kv per u64 word) ----------------
__global__ __launch_bounds__(256) void cvt_mask_bits(const int* __restrict__ in,
                                                     u64* __restrict__ out) {
  size_t w = ((size_t)blockIdx.x * 256 + threadIdx.x) >> 6;
  int lane = threadIdx.x & 63;
  int v = in[w * 64 + lane];
  u64 bits = __ballot(v != 0);  // bit l = (mask[w*64+l] != 0)
  if (lane == 0) out[w] = bits;
}

// ------- W[K][N] f32 -> WT[N][K] bf16, all four weights in one launch -------
__global__ __launch_bounds__(256) void transpose_cvt_w4(const float* __restrict__ W0,
                                                        const float* __restrict__ W1,
                                                        const float* __restrict__ W2,
                                                        const float* __restrict__ W3,
                                                        u16* __restrict__ WTbase) {
  __shared__ u16 t[64][65];
  const int z = blockIdx.z;
  const float* W = (z == 0) ? W0 : (z == 1) ? W1 : (z == 2) ? W2 : W3;
  u16* WT = WTbase + (size_t)z * DDIM * DDIM;
  const int k0 = blockIdx.x * 64, n0 = blockIdx.y * 64;
  const int tid = threadIdx.x;
  const int r = tid >> 4;          // 0..15
  const int c4 = (tid & 15) * 4;   // col group
#pragma unroll
  for (int it = 0; it < 4; ++it) {
    int k = r + it * 16;
    float4 v = *(const float4*)&W[(size_t)(k0 + k) * DDIM + n0 + c4];
    t[c4 + 0][k] = f2bf(v.x);
    t[c4 + 1][k] = f2bf(v.y);
    t[c4 + 2][k] = f2bf(v.z);
    t[c4 + 3][k] = f2bf(v.w);
  }
  __syncthreads();
#pragma unroll
  for (int it = 0; it < 4; ++it) {
    int n = r + it * 16;
    uint2 o;
    u16* po = (u16*)&o;
#pragma unroll
    for (int j = 0; j < 4; ++j) po[j] = t[n][c4 + j];
    *(uint2*)&WT[(size_t)(n0 + n) * DDIM + k0 + c4] = o;
  }
}

// ---------------- Vp (B,S,D) bf16 -> VpT (B*H, HD, S) bf16 ----------------
__global__ __launch_bounds__(256) void transpose_v(const u16* __restrict__ Vp,
                                                   u16* __restrict__ VpT) {
  __shared__ u16 t[64][65];
  const int bh = blockIdx.y, b = bh >> 4, h = bh & 15;
  const int s0 = blockIdx.x * 64;
  const int tid = threadIdx.x;
  const int r = tid >> 3;        // 0..31
  const int c8 = (tid & 7) * 8;  // 8-elem chunk
  const u16* src = Vp + ((size_t)(b * SS + s0)) * DDIM + h * 64;
#pragma unroll
  for (int it = 0; it < 2; ++it) {
    int s = r + it * 32;
    int4 v = *(const int4*)(src + (size_t)s * DDIM + c8);
    u16* pv = (u16*)&v;
#pragma unroll
    for (int j = 0; j < 8; ++j) t[c8 + j][s] = pv[j];
  }
  __syncthreads();
  u16* dst = VpT + (size_t)bh * 64 * SS + s0;
#pragma unroll
  for (int it = 0; it < 2; ++it) {
    int d = r + it * 32;
    int4 o;
    u16* po = (u16*)&o;
#pragma unroll
    for (int j = 0; j < 8; ++j) po[j] = t[d][c8 + j];
    *(int4*)(dst + (size_t)d * SS + c8) = o;
  }
}

// ---------------- GEMM: 128x128 tile, BK=64, 2-phase double-buffer ----------
// MODE 0: fused QKV. A = Abase + sel*4M (sel = colB0>>10), BT spans 3072 rows,
//         bias b0/b1/b2 by sel, bf16 out to C + sel*4M.
//         Q (sel 0) scaled by 0.125*log2(e) (exp2-domain softmax).
// MODE 1: plain, f32 out, bias b0.
template <int MODE>
__global__ __launch_bounds__(256) void gemm_bt(const u16* __restrict__ Abase,
                                               const u16* __restrict__ BT,
                                               const float* __restrict__ b0,
                                               const float* __restrict__ b1,
                                               const float* __restrict__ b2,
                                               void* __restrict__ C) {
  __shared__ __align__(16) u16 Al[2][128][64];
  __shared__ __align__(16) u16 Bl[2][128][64];
  const int tid = threadIdx.x;
  const int wid = tid >> 6, lane = tid & 63;
  const int wm = (wid >> 1) * 64, wn = (wid & 1) * 64;
  const int rowA0 = blockIdx.x * 128, colB0 = blockIdx.y * 128;
  const int sel = (MODE == 0) ? (colB0 >> 10) : 0;
  const u16* Ag = Abase + (size_t)sel * ((size_t)MROWS * DDIM) + (size_t)rowA0 * DDIM;
  const u16* Bg = BT + (size_t)colB0 * DDIM;
  f32x4 acc[4][4] = {};
  const int rl = lane >> 3;        // 0..7
  const int ce = (lane & 7) * 8;   // chunk offset (elems)

#define G_STAGE(buf, kt)                                                       \
  do {                                                                         \
    _Pragma("unroll") for (int c = 0; c < 4; ++c) {                            \
      int rt = wid * 32 + c * 8;                                               \
      __builtin_amdgcn_global_load_lds(                                        \
          (GASV*)(Ag + (size_t)(rt + rl) * DDIM + (kt) + ce),                  \
          (LASV*)((char*)&Al[buf][0][0] + rt * 128), 16, 0, 0);                \
      __builtin_amdgcn_global_load_lds(                                        \
          (GASV*)(Bg + (size_t)(rt + rl) * DDIM + (kt) + ce),                  \
          (LASV*)((char*)&Bl[buf][0][0] + rt * 128), 16, 0, 0);                \
    }                                                                          \
  } while (0)

  G_STAGE(0, 0);
  __syncthreads();
  for (int t = 0; t < 16; ++t) {  // K = 1024 = 16 * 64
    const int cur = t & 1;
    if (t < 15) G_STAGE(cur ^ 1, (t + 1) * 64);
#pragma unroll
    for (int kk = 0; kk < 64; kk += 32) {
      bf16x8 af[4], bfr[4];
#pragma unroll
      for (int i = 0; i < 4; ++i)
        af[i] = *(const bf16x8*)&Al[cur][wm + i * 16 + (lane & 15)][kk + (lane >> 4) * 8];
#pragma unroll
      for (int j = 0; j < 4; ++j)
        bfr[j] = *(const bf16x8*)&Bl[cur][wn + j * 16 + (lane & 15)][kk + (lane >> 4) * 8];
#pragma unroll
      for (int i = 0; i < 4; ++i)
#pragma unroll
        for (int j = 0; j < 4; ++j)
          acc[i][j] = __builtin_amdgcn_mfma_f32_16x16x32_bf16(af[i], bfr[j], acc[i][j], 0, 0, 0);
    }
    __syncthreads();
  }
#undef G_STAGE

  if (MODE == 0) {
    const float* bp = (sel == 0) ? b0 : (sel == 1 ? b1 : b2);
    // fold 1/sqrt(HD) and log2(e) into Q (softmax runs in exp2 domain)
    const float scale = (sel == 0) ? 0.125f * 1.44269504088896340736f : 1.0f;
    u16* dst = (u16*)C + (size_t)sel * ((size_t)MROWS * DDIM);
    const int colw0 = (colB0 & 1023) + wn;
#pragma unroll
    for (int i = 0; i < 4; ++i)
#pragma unroll
      for (int j = 0; j < 4; ++j) {
        int colw = colw0 + j * 16 + (lane & 15);
        float bv = bp[colw];
#pragma unroll
        for (int r = 0; r < 4; ++r) {
          int row = rowA0 + wm + i * 16 + (lane >> 4) * 4 + r;
          dst[(size_t)row * DDIM + colw] = f2bf((acc[i][j][r] + bv) * scale);
        }
      }
  } else {
#pragma unroll
    for (int i = 0; i < 4; ++i)
#pragma unroll
      for (int j = 0; j < 4; ++j) {
        int col = colB0 + wn + j * 16 + (lane & 15);
        float bv = b0[col];
#pragma unroll
        for (int r = 0; r < 4; ++r) {
          int row = rowA0 + wm + i * 16 + (lane >> 4) * 4 + r;
          ((float*)C)[(size_t)row * DDIM + col] = acc[i][j][r] + bv;
        }
      }
  }
}

// ---------------- Flash attention (swapped QK^T, per-lane q-row) ------------
// grid: 1024 blocks (XCD-swizzled). 4 waves; wave w owns q-rows [w*16,w*16+16).
// Lane (cbase=lane&15, hi=lane>>4) owns softmax state for q=cbase.
// Mask folded into exp2 arg: p = exp2(fma(bit,-512,s) - m); raw-score max.
__global__ __launch_bounds__(256, 4) void attn_fwd(const u16* __restrict__ Qp,
                                                   const u16* __restrict__ Kp,
                                                   const u16* __restrict__ VpT,
                                                   const u64* __restrict__ Mbits,
                                                   u16* __restrict__ O) {
  __shared__ __align__(16) u16 Kl[2][64][64];  // [buf][kv][d], swizzled
  __shared__ __align__(16) u16 Vl[2][64][64];  // [buf][d][kv], swizzled
  __shared__ __align__(16) u16 Pl[4][16][64];  // per-wave P [q][kv], swizzled
  const int tid = threadIdx.x, wid = tid >> 6, lane = tid & 63;
  // XCD swizzle: 8 XCDs x (4 bh x 32 q-tiles) -> K/V of a head stays on 1 XCD
  const int bid = blockIdx.x;
  const int bh = (bid & 7) * 4 + ((bid >> 3) & 3);
  const int q0 = (bid >> 5) * 64;
  const int b = bh >> 4, h = bh & 15;
  const int hi = lane >> 4, cbase = lane & 15, lx = lane & 7;

  bf16x8 qf[2];
  {
    const u16* qb = Qp + (size_t)(b * SS + q0 + wid * 16 + cbase) * DDIM + h * 64 + hi * 8;
    qf[0] = *(const bf16x8*)qb;
    qf[1] = *(const bf16x8*)(qb + 32);
  }
  float m_run = -1e30f, l_run = 0.f;
  f32x4 accO[4];
#pragma unroll
  for (int f = 0; f < 4; ++f) accO[f] = (f32x4){0.f, 0.f, 0.f, 0.f};

  const u16* Kgb = Kp + (size_t)b * SS * DDIM + h * 64;
  const u16* Vgb = VpT + (size_t)bh * 64 * SS;
  const u64* Mb = Mbits + (size_t)(b * SS + q0 + wid * 16 + cbase) * (SS / 64);
  const int rl = lane >> 3;
  const int ceS = ((lane & 7) ^ rl) * 8;  // pre-swizzled source chunk

  // hoisted LDS fragment offsets (u16 units within one 64x64 tile):
  // fo[f][ks] serves K-frag (f=fn), V-frag (f=nd) and P-read (f=0).
  int fo[4][2];
#pragma unroll
  for (int f = 0; f < 4; ++f)
#pragma unroll
    for (int ks = 0; ks < 2; ++ks)
      fo[f][ks] = (f * 16 + cbase) * 64 + (((ks * 4 + hi) ^ lx) << 3);
  int pw[4];
#pragma unroll
  for (int f = 0; f < 4; ++f)
    pw[f] = cbase * 64 + (((f * 2 + (hi >> 1)) ^ lx) << 3) + ((hi & 1) << 2);
  u16* KlF = &Kl[0][0][0];
  u16* VlF = &Vl[0][0][0];
  u16* Plw = &Pl[wid][0][0];

#define STAGE_KV(BUF, kv)                                                      \
  do {                                                                         \
    _Pragma("unroll") for (int c = 0; c < 2; ++c) {                            \
      int rt = wid * 16 + c * 8;                                               \
      __builtin_amdgcn_global_load_lds(                                        \
          (GASV*)(Kgb + (size_t)((kv) + rt + rl) * DDIM + ceS),                \
          (LASV*)((char*)KlF + (BUF) * 8192 + rt * 128), 16, 0, 0);            \
      __builtin_amdgcn_global_load_lds(                                        \
          (GASV*)(Vgb + (size_t)(rt + rl) * SS + (kv) + ceS),                  \
          (LASV*)((char*)VlF + (BUF) * 8192 + rt * 128), 16, 0, 0);            \
    }                                                                          \
  } while (0)

#define ATTN_ITER(T, CUR, DO_STAGE)                                            \
  do {                                                                         \
    u64 mrow = Mb[T];                                                          \
    if (DO_STAGE) STAGE_KV((CUR) ^ 1, ((T) + 1) * 64);                         \
    f32x4 sc[4];                                                               \
    __builtin_amdgcn_s_setprio(1);                                             \
    _Pragma("unroll") for (int fn = 0; fn < 4; ++fn) {                         \
      f32x4 c = (f32x4){0.f, 0.f, 0.f, 0.f};                                   \
      _Pragma("unroll") for (int ks = 0; ks < 2; ++ks) {                       \
        bf16x8 kf = *(const bf16x8*)(KlF + (CUR) * 4096 + fo[fn][ks]);         \
        c = __builtin_amdgcn_mfma_f32_16x16x32_bf16(kf, qf[ks], c, 0, 0, 0);   \
      }                                                                        \
      sc[fn] = c;                                                              \
    }                                                                          \
    __builtin_amdgcn_s_setprio(0);                                             \
    /* raw-score row max (mask not applied; any consistent m is valid) */      \
    float pmax;                                                                \
    {                                                                          \
      float a0 = fmaxf(fmaxf(sc[0][0], sc[0][1]), fmaxf(sc[0][2], sc[0][3]));  \
      float a1 = fmaxf(fmaxf(sc[1][0], sc[1][1]), fmaxf(sc[1][2], sc[1][3]));  \
      float a2 = fmaxf(fmaxf(sc[2][0], sc[2][1]), fmaxf(sc[2][2], sc[2][3]));  \
      float a3 = fmaxf(fmaxf(sc[3][0], sc[3][1]), fmaxf(sc[3][2], sc[3][3]));  \
      pmax = fmaxf(fmaxf(a0, a1), fmaxf(a2, a3));                              \
      pmax = fmaxf(pmax, __shfl_xor(pmax, 16, 64));                            \
      pmax = fmaxf(pmax, __shfl_xor(pmax, 32, 64));                            \
    }                                                                          \
    if (!__all(pmax <= m_run + 8.f)) { /* defer-max rescale */                 \
      float mnew = fmaxf(m_run, pmax);                                         \
      float alpha = dev_exp2(m_run - mnew);                                    \
      m_run = mnew;                                                            \
      l_run *= alpha;                                                          \
      float ab[4];                                                             \
      _Pragma("unroll") for (int j = 0; j < 4; ++j)                            \
          ab[j] = __shfl(alpha, (lane & 48) + hi * 4 + j, 64);                 \
      _Pragma("unroll") for (int nd = 0; nd < 4; ++nd)                         \
          _Pragma("unroll") for (int j = 0; j < 4; ++j) accO[nd][j] *= ab[j];  \
    }                                                                          \
    /* p = exp2(s - m - 512*maskbit); masked -> exact 0 via underflow */       \
    u64 mh = mrow >> (hi * 4);                                                 \
    u32 mlo = (u32)mh, mhi2 = (u32)(mh >> 32);                                 \
    float rs0 = 0.f, rs1 = 0.f;                                                \
    _Pragma("unroll") for (int fn = 0; fn < 4; ++fn) {                         \
      u32 b4 = ((fn < 2) ? mlo : mhi2) >> ((fn & 1) * 16);                     \
      _Pragma("unroll") for (int j = 0; j < 4; ++j) {                          \
        float bf_ = (float)((b4 >> j) & 1u);                                   \
        float p = dev_exp2(fmaf(bf_, -512.f, sc[fn][j]) - m_run);              \
        sc[fn][j] = p;                                                         \
        if (j & 1) rs1 += p; else rs0 += p;                                    \
      }                                                                        \
    }                                                                          \
    float rsum = rs0 + rs1;                                                    \
    rsum += __shfl_xor(rsum, 16, 64);                                          \
    rsum += __shfl_xor(rsum, 32, 64);                                          \
    l_run += rsum;                                                             \
    _Pragma("unroll") for (int fn = 0; fn < 4; ++fn) {                         \
      uint2 wpair;                                                             \
      wpair.x = cvt_pk_bf16(sc[fn][0], sc[fn][1]);                             \
      wpair.y = cvt_pk_bf16(sc[fn][2], sc[fn][3]);                             \
      *(uint2*)(Plw + pw[fn]) = wpair;                                         \
    }                                                                          \
    bf16x8 pf0 = *(const bf16x8*)(Plw + fo[0][0]);                             \
    bf16x8 pf1 = *(const bf16x8*)(Plw + fo[0][1]);                             \
    __builtin_amdgcn_s_setprio(1);                                             \
    _Pragma("unroll") for (int nd = 0; nd < 4; ++nd) {                         \
      bf16x8 v0 = *(const bf16x8*)(VlF + (CUR) * 4096 + fo[nd][0]);            \
      bf16x8 v1 = *(const bf16x8*)(VlF + (CUR) * 4096 + fo[nd][1]);            \
      accO[nd] = __builtin_amdgcn_mfma_f32_16x16x32_bf16(pf0, v0, accO[nd], 0, 0, 0); \
      accO[nd] = __builtin_amdgcn_mfma_f32_16x16x32_bf16(pf1, v1, accO[nd], 0, 0, 0); \
    }                                                                          \
    __builtin_amdgcn_s_setprio(0);                                             \
    __syncthreads();                                                           \
  } while (0)

  STAGE_KV(0, 0);
  __syncthreads();
  for (int th = 0; th < 16; ++th) {  // 32 kv-tiles, unrolled x2 (CUR static)
    ATTN_ITER(2 * th, 0, true);
    ATTN_ITER(2 * th + 1, 1, (th != 15));
  }
#undef ATTN_ITER
#undef STAGE_KV

  // l for output rows q=hi*4+j lives in lane with cbase=hi*4+j
  float lb[4];
#pragma unroll
  for (int j = 0; j < 4; ++j)
    lb[j] = __shfl(l_run, (lane & 48) + hi * 4 + j, 64);
#pragma unroll
  for (int nd = 0; nd < 4; ++nd)
#pragma unroll
    for (int j = 0; j < 4; ++j) {
      int row = q0 + wid * 16 + hi * 4 + j;
      int col = h * 64 + nd * 16 + cbase;
      O[(size_t)(b * SS + row) * DDIM + col] = f2bf(accO[nd][j] / lb[j]);
    }
}

// ---------------- residual + LayerNorm (ddof=1, std+eps) ----------------
__global__ __launch_bounds__(256) void ln_res(const float* __restrict__ qin,
                                              const float* __restrict__ proj,
                                              const float* __restrict__ gamma,
                                              const float* __restrict__ beta,
                                              float* __restrict__ out) {
  const int row = blockIdx.x, tid = threadIdx.x;
  const size_t base = (size_t)row * DDIM + tid * 4;
  float4 a = *(const float4*)(qin + base);
  float4 p = *(const float4*)(proj + base);
  float x0 = a.x + p.x, x1 = a.y + p.y, x2 = a.z + p.z, x3 = a.w + p.w;
  float s = x0 + x1 + x2 + x3;
  __shared__ float red[4];
#pragma unroll
  for (int off = 32; off >= 1; off >>= 1) s += __shfl_xor(s, off, 64);
  const int wid = tid >> 6, lane = tid & 63;
  if (lane == 0) red[wid] = s;
  __syncthreads();
  float mean = (red[0] + red[1] + red[2] + red[3]) * (1.0f / DDIM);
  float d0 = x0 - mean, d1 = x1 - mean, d2 = x2 - mean, d3 = x3 - mean;
  float ss = d0 * d0 + d1 * d1 + d2 * d2 + d3 * d3;
#pragma unroll
  for (int off = 32; off >= 1; off >>= 1) ss += __shfl_xor(ss, off, 64);
  __syncthreads();
  if (lane == 0) red[wid] = ss;
  __syncthreads();
  float var = (red[0] + red[1] + red[2] + red[3]) * (1.0f / (DDIM - 1));
  float denom = sqrtf(var) + 1e-6f;
  float4 g = *(const float4*)(gamma + (size_t)tid * 4);
  float4 be = *(const float4*)(beta + (size_t)tid * 4);
  float4 o;
  o.x = g.x * d0 / denom + be.x;
  o.y = g.y * d1 / denom + be.y;
  o.z = g.z * d2 / denom + be.z;
  o.w = g.w * d3 / denom + be.w;
  *(float4*)(out + base) = o;
}

extern "C" void kernel_launch(void* const* d_in, const int* in_sizes, int n_in,
                              void* d_out, int out_size, void* d_ws, size_t ws_size,
                              hipStream_t stream) {
  const float* query = (const float*)d_in[0];
  const float* key = (const float*)d_in[1];
  const float* value = (const float*)d_in[2];
  const int* mask = (const int*)d_in[3];  // bool passed as int32
  const float* Wq = (const float*)d_in[4];
  const float* bq = (const float*)d_in[5];
  const float* Wk = (const float*)d_in[6];
  const float* bk = (const float*)d_in[7];
  const float* Wv = (const float*)d_in[8];
  const float* bv = (const float*)d_in[9];
  const float* Wo = (const float*)d_in[10];
  const float* bo = (const float*)d_in[11];
  const float* gamma = (const float*)d_in[12];
  const float* beta = (const float*)d_in[13];
  float* out = (float*)d_out;
  char* ws = (char*)d_ws;
  const size_t MB = 1ull << 20;
  // Workspace map (64 MB):
  u16* qkvb = (u16*)(ws + 0 * MB);  // 24MB qb/kb/vb contiguous
  u16* WT = (u16*)(ws + 24 * MB);   // 8MB: WqT,WkT,WvT,WoT contiguous
  u16* WoT = (u16*)(ws + 30 * MB);
  u16* Qp = (u16*)(ws + 32 * MB);   // Qp/Kp/Vp contiguous (8MB stride)
  u16* Kp = (u16*)(ws + 40 * MB);
  u16* Vp = (u16*)(ws + 48 * MB);
  u16* VpT = (u16*)(ws + 16 * MB);  // over vb (dead after QKV-GEMM)
  u16* attnb = (u16*)(ws + 56 * MB); // 8MB
  u64* maskbits = (u64*)(ws + 0 * MB);   // 1MB over qb (dead after QKV-GEMM)
  float* proj = (float*)(ws + 8 * MB);   // 16MB over kb+vb/VpT (after attn)

  cvt_bf16_3<<<dim3(MROWS * DDIM / 1024, 3), 256, 0, stream>>>(query, key, value, qkvb);
  transpose_cvt_w4<<<dim3(16, 16, 4), 256, 0, stream>>>(Wq, Wk, Wv, Wo, WT);
  // fused QKV projection: A-select and out-select by colB0>>10
  gemm_bt<0><<<dim3(MROWS / 128, 3 * DDIM / 128), 256, 0, stream>>>(
      qkvb, WT, bq, bk, bv, Qp);
  // mask bitpack after QKV-GEMM (qb region dead)
  cvt_mask_bits<<<(NB * SS * SS) / 256, 256, 0, stream>>>(mask, maskbits);
  transpose_v<<<dim3(SS / 64, NB * NH), 256, 0, stream>>>(Vp, VpT);
  attn_fwd<<<1024, 256, 0, stream>>>(Qp, Kp, VpT, maskbits, attnb);
  gemm_bt<1><<<dim3(MROWS / 128, DDIM / 128), 256, 0, stream>>>(
      attnb, WoT, bo, nullptr, nullptr, proj);
  ln_res<<<MROWS, 256, 0, stream>>>(query, proj, gamma, beta, out);
}